// Round 18
// baseline (72.279 us; speedup 1.0000x reference)
//
#include <hip/hip_runtime.h>
#include <hip/hip_bf16.h>

// SelfAttention b=2, heads=8, D=32, n=4096 (64x64).
// Pass 1 (proj_kernel, z=Q/K/V): x -> Q bf16 [bg][n][32] (pre-scaled by
//   SCALE*log2e), K2 bf16 [bg][dgrp=d/8][key][8], V2 bf16 sigma-ordered
//   [bg][key16grp][h][d][8] (r15-proven: PV A-frags = direct cvt_pk of
//   exp2 outputs, no cross-lane ops).
// Pass 2 (attn_kernel): 32x32 MFMA flash attention, 32 q/wave.
//   r17-proven loop: unroll x2 (two independent S->exp2->PV chains/iter),
//   K prefetch 1 pair ahead, lsum on the matrix pipe via mfma(P,ones).
//   r18: KEY-SPLIT -- 4 waves/block = (qhalf, khalf); khalf halves the
//   key range (32 pairs each) -> 4096 waves -> 4 waves/SIMD so the two
//   ~50%-busy pipes (r17: VALU 53 / MFMA 36) can interleave across more
//   contexts. Merge: khalf=1 writes fp32 oacc+lsacc to LDS (lane-major,
//   conflict-free), one __syncthreads, khalf=0 adds + runs the proven
//   endgame (LDS transpose -> Wp MFMA -> float4 stores).

constexpr int D = 32;
constexpr int N = 4096;
constexpr int NBG = 16;
constexpr float SCALE = 0.17677669529663687f;   // 32^-0.5
constexpr float LOG2E = 1.4426950408889634f;

using bfrag  = __attribute__((ext_vector_type(8))) short;   // 8 bf16
using s16x8  = __attribute__((ext_vector_type(8))) short;
using f32x16 = __attribute__((ext_vector_type(16))) float;
typedef unsigned short u16;
typedef unsigned int u32;

constexpr int PSTR = 34;            // endgame tile row stride in u16

__device__ __forceinline__ float fexp2(float x) { return __builtin_amdgcn_exp2f(x); }

__device__ __forceinline__ short f2bfs(float f) {
    __hip_bfloat16 h = __float2bfloat16(f);
    return (short)__builtin_bit_cast(u16, h);
}

__device__ __forceinline__ u32 cvt_pk_bf16(float lo, float hi) {
    u32 r;
    asm("v_cvt_pk_bf16_f32 %0, %1, %2" : "=v"(r) : "v"(lo), "v"(hi));
    return r;
}

// ---------------- pass 1: projections -> fragment-native bf16 scratch -----
__global__ __launch_bounds__(256) void proj_kernel(
    const float* __restrict__ x,
    const float* __restrict__ Wq, const float* __restrict__ bq,
    const float* __restrict__ Wk, const float* __restrict__ bk,
    const float* __restrict__ Wv, const float* __restrict__ bv,
    u16* __restrict__ Qb, u16* __restrict__ K2, u16* __restrict__ V2) {
    const int bg = blockIdx.y, g = bg & 7;
    const int z  = blockIdx.z;                       // 0=Q 1=K 2=V
    const int i  = blockIdx.x * 256 + threadIdx.x;   // key / pixel index

    const float* W  = (z == 0) ? Wq : (z == 1) ? Wk : Wv;
    const float* bb = (z == 0) ? bq : (z == 1) ? bk : bv;

    const float* xb = x + (size_t)bg * D * N;
    float xv[D];
#pragma unroll
    for (int d = 0; d < D; ++d) xv[d] = xb[(size_t)d * N + i];

    const float* w = W + g * D * D;
    float acc[D];
#pragma unroll
    for (int o = 0; o < D; ++o) {
        float a0 = 0.f, a1 = 0.f, a2 = 0.f, a3 = 0.f;
#pragma unroll
        for (int d = 0; d < D; d += 4) {
            a0 = fmaf(w[o * D + d    ], xv[d    ], a0);
            a1 = fmaf(w[o * D + d + 1], xv[d + 1], a1);
            a2 = fmaf(w[o * D + d + 2], xv[d + 2], a2);
            a3 = fmaf(w[o * D + d + 3], xv[d + 3], a3);
        }
        acc[o] = (a0 + a1) + (a2 + a3) + bb[g * D + o];
    }

    if (z == 0) {                                    // Q -> row [n][32]
        u16* dst = Qb + ((size_t)bg * N + i) * D;
#pragma unroll
        for (int t = 0; t < 4; ++t) {
            s16x8 v;
#pragma unroll
            for (int e = 0; e < 8; ++e) v[e] = f2bfs(acc[8 * t + e] * (SCALE * LOG2E));
            *reinterpret_cast<s16x8*>(dst + 8 * t) = v;
        }
    } else if (z == 1) {                             // K -> [dgrp][key][8]
        u16* kb2 = K2 + (size_t)bg * N * D;
#pragma unroll
        for (int t = 0; t < 4; ++t) {                // dgrp = t
            s16x8 v;
#pragma unroll
            for (int e = 0; e < 8; ++e) v[e] = f2bfs(acc[8 * t + e]);
            *reinterpret_cast<s16x8*>(kb2 + (size_t)t * N * 8 + (size_t)i * 8) = v;
        }
    } else {
        // V -> sigma-ordered [key16grp][h][d][8]:
        // key j=i&15 sits at h=(j>>2)&1, e=(j&3)+4*((j>>3)&1), matching the
        // S^T in-lane key order (row = (e&3)+8*(e>>2)+4h) -> no permswap.
        const int j  = i & 15;
        const int hh = (j >> 2) & 1;
        const int ee = (j & 3) + 4 * ((j >> 3) & 1);
        u16* vb2 = V2 + (size_t)bg * N * D + (size_t)(i >> 4) * 512 + hh * 256 + ee;
#pragma unroll
        for (int o = 0; o < D; ++o)
            vb2[o * 8] = (u16)f2bfs(acc[o]);
    }
}

// ---------------- pass 2: 32x32 MFMA flash attention, key-split ------------
__global__ __launch_bounds__(256) void attn_kernel(
    const u16* __restrict__ Qb, const u16* __restrict__ K2, const u16* __restrict__ V2,
    const float* __restrict__ Wp, const float* __restrict__ bp,
    float* __restrict__ out) {
    const int s = blockIdx.x;
    const int bg = s & 15, qt = s >> 4, g = bg & 7;   // bg fastest -> XCD L2 reuse
    const int wid = threadIdx.x >> 6;
    const int qhalf = wid >> 1, khalf = wid & 1;
    const int lane = threadIdx.x & 63;
    const int l31 = lane & 31, h = lane >> 5;
    const int qbase = qt * 64 + qhalf * 32;           // 32 q rows per wave

    __shared__ float macc[2][32][64];                 // khalf merge (16 KB)
    __shared__ u16 plds_all[2][32][PSTR];             // endgame transpose
    u16* tile = &plds_all[qhalf][0][0];

    const u16* Qw = Qb + (size_t)bg * N * D;
    const u16* Kw = K2 + (size_t)bg * N * D;
    const u16* Vw = V2 + (size_t)bg * N * D;

    // Q B-fragments (col=q=l31, k-slots d=8h+e), held whole loop
    const u16* qrow = Qw + (size_t)(qbase + l31) * D + 8 * h;
    bfrag qf0 = *reinterpret_cast<const bfrag*>(qrow);
    bfrag qf1 = *reinterpret_cast<const bfrag*>(qrow + 16);

    // Wp B-fragments (col=o=l31, k-slots d=8h+e) + bias
    bfrag wf0, wf1;
    {
        const float* wrow = Wp + (size_t)(g * D + l31) * D + 8 * h;
#pragma unroll
        for (int e = 0; e < 8; ++e) { wf0[e] = f2bfs(wrow[e]); wf1[e] = f2bfs(wrow[16 + e]); }
    }
    const float bias = bp[g * D + l31];

    // ones B-fragment (bf16 1.0) for the lsum MFMA
    bfrag onesf;
#pragma unroll
    for (int e = 0; e < 8; ++e) onesf[e] = (short)0x3F80;

    const f32x16 zf16 = {};
    f32x16 oacc  = {};
    f32x16 lsacc = {};

    // fragment-native bases + this wave's key-half offset
    const u16* kBase   = Kw + (size_t)h * N * 8 + (size_t)l31 * 8 + (size_t)khalf * (N / 2) * 8;
    const u16* kHiBase = kBase + 2 * N * 8;
    const u16* vBase   = Vw + h * 256 + l31 * 8 + (size_t)khalf * (N / 2) * 32;

    const int NTL = (N / 2) / 32;    // 64 local tiles per wave
    const int NPL = NTL / 2;         // 32 local pairs

    auto ldK = [&](int tt, int hi) {
        return *reinterpret_cast<const bfrag*>((hi ? kHiBase : kBase) + (size_t)tt * 256);
    };
    auto ldV = [&](int tt, int half) {
        return *reinterpret_cast<const bfrag*>(vBase + (size_t)tt * 1024 + half * 512);
    };

    // ---- prologue: S for local tiles 0,1; K for tiles 2,3 ----
    bfrag kA0 = ldK(0, 0), kA1 = ldK(0, 1);
    bfrag kB0 = ldK(1, 0), kB1 = ldK(1, 1);
    bfrag vA0 = ldV(0, 0), vA1 = ldV(0, 1);
    bfrag vB0 = ldV(1, 0), vB1 = ldV(1, 1);

    f32x16 sA = __builtin_amdgcn_mfma_f32_32x32x16_bf16(kA0, qf0, zf16, 0, 0, 0);
    sA = __builtin_amdgcn_mfma_f32_32x32x16_bf16(kA1, qf1, sA, 0, 0, 0);
    f32x16 sB = __builtin_amdgcn_mfma_f32_32x32x16_bf16(kB0, qf0, zf16, 0, 0, 0);
    sB = __builtin_amdgcn_mfma_f32_32x32x16_bf16(kB1, qf1, sB, 0, 0, 0);

    kA0 = ldK(2, 0); kA1 = ldK(2, 1);
    kB0 = ldK(3, 0); kB1 = ldK(3, 1);

    for (int t = 0; t < NPL - 1; ++t) {
        // S for pair t+1 -- independent of this pair's VALU work
        f32x16 snA = __builtin_amdgcn_mfma_f32_32x32x16_bf16(kA0, qf0, zf16, 0, 0, 0);
        snA = __builtin_amdgcn_mfma_f32_32x32x16_bf16(kA1, qf1, snA, 0, 0, 0);
        f32x16 snB = __builtin_amdgcn_mfma_f32_32x32x16_bf16(kB0, qf0, zf16, 0, 0, 0);
        snB = __builtin_amdgcn_mfma_f32_32x32x16_bf16(kB1, qf1, snB, 0, 0, 0);

        // prefetch K for pair t+2 (clamped), V for pair t+1
        const int t4 = (2 * t + 4 < NTL) ? (2 * t + 4) : (NTL - 1);
        const int t5 = (2 * t + 5 < NTL) ? (2 * t + 5) : (NTL - 1);
        kA0 = ldK(t4, 0); kA1 = ldK(t4, 1);
        kB0 = ldK(t5, 0); kB1 = ldK(t5, 1);
        bfrag vnA0 = ldV(2 * t + 2, 0), vnA1 = ldV(2 * t + 2, 1);
        bfrag vnB0 = ldV(2 * t + 3, 0), vnB1 = ldV(2 * t + 3, 1);

        // chain A: exp2 -> pack -> PV
        {
            float p[16];
#pragma unroll
            for (int r = 0; r < 16; ++r) p[r] = fexp2(sA[r]);
            uint4 f1 = make_uint4(cvt_pk_bf16(p[0],  p[1]),  cvt_pk_bf16(p[2],  p[3]),
                                  cvt_pk_bf16(p[4],  p[5]),  cvt_pk_bf16(p[6],  p[7]));
            uint4 f2 = make_uint4(cvt_pk_bf16(p[8],  p[9]),  cvt_pk_bf16(p[10], p[11]),
                                  cvt_pk_bf16(p[12], p[13]), cvt_pk_bf16(p[14], p[15]));
            const bfrag pf1 = __builtin_bit_cast(bfrag, f1);
            const bfrag pf2 = __builtin_bit_cast(bfrag, f2);
            oacc  = __builtin_amdgcn_mfma_f32_32x32x16_bf16(pf1, vA0,   oacc,  0, 0, 0);
            oacc  = __builtin_amdgcn_mfma_f32_32x32x16_bf16(pf2, vA1,   oacc,  0, 0, 0);
            lsacc = __builtin_amdgcn_mfma_f32_32x32x16_bf16(pf1, onesf, lsacc, 0, 0, 0);
            lsacc = __builtin_amdgcn_mfma_f32_32x32x16_bf16(pf2, onesf, lsacc, 0, 0, 0);
        }
        // chain B: exp2 -> pack -> PV
        {
            float p[16];
#pragma unroll
            for (int r = 0; r < 16; ++r) p[r] = fexp2(sB[r]);
            uint4 f1 = make_uint4(cvt_pk_bf16(p[0],  p[1]),  cvt_pk_bf16(p[2],  p[3]),
                                  cvt_pk_bf16(p[4],  p[5]),  cvt_pk_bf16(p[6],  p[7]));
            uint4 f2 = make_uint4(cvt_pk_bf16(p[8],  p[9]),  cvt_pk_bf16(p[10], p[11]),
                                  cvt_pk_bf16(p[12], p[13]), cvt_pk_bf16(p[14], p[15]));
            const bfrag pf1 = __builtin_bit_cast(bfrag, f1);
            const bfrag pf2 = __builtin_bit_cast(bfrag, f2);
            oacc  = __builtin_amdgcn_mfma_f32_32x32x16_bf16(pf1, vB0,   oacc,  0, 0, 0);
            oacc  = __builtin_amdgcn_mfma_f32_32x32x16_bf16(pf2, vB1,   oacc,  0, 0, 0);
            lsacc = __builtin_amdgcn_mfma_f32_32x32x16_bf16(pf1, onesf, lsacc, 0, 0, 0);
            lsacc = __builtin_amdgcn_mfma_f32_32x32x16_bf16(pf2, onesf, lsacc, 0, 0, 0);
        }

        sA = snA; sB = snB;
        vA0 = vnA0; vA1 = vnA1; vB0 = vnB0; vB1 = vnB1;
    }

    // ---- epilogue: final local pair ----
#pragma unroll
    for (int c = 0; c < 2; ++c) {
        const f32x16& sc = c ? sB : sA;
        float p[16];
#pragma unroll
        for (int r = 0; r < 16; ++r) p[r] = fexp2(sc[r]);
        uint4 f1 = make_uint4(cvt_pk_bf16(p[0],  p[1]),  cvt_pk_bf16(p[2],  p[3]),
                              cvt_pk_bf16(p[4],  p[5]),  cvt_pk_bf16(p[6],  p[7]));
        uint4 f2 = make_uint4(cvt_pk_bf16(p[8],  p[9]),  cvt_pk_bf16(p[10], p[11]),
                              cvt_pk_bf16(p[12], p[13]), cvt_pk_bf16(p[14], p[15]));
        const bfrag pf1 = __builtin_bit_cast(bfrag, f1);
        const bfrag pf2 = __builtin_bit_cast(bfrag, f2);
        oacc  = __builtin_amdgcn_mfma_f32_32x32x16_bf16(pf1, c ? vB0 : vA0, oacc,  0, 0, 0);
        oacc  = __builtin_amdgcn_mfma_f32_32x32x16_bf16(pf2, c ? vB1 : vA1, oacc,  0, 0, 0);
        lsacc = __builtin_amdgcn_mfma_f32_32x32x16_bf16(pf1, onesf, lsacc, 0, 0, 0);
        lsacc = __builtin_amdgcn_mfma_f32_32x32x16_bf16(pf2, onesf, lsacc, 0, 0, 0);
    }

    // ---- merge the two key-half waves of each q subtile ----
    if (khalf == 1) {
#pragma unroll
        for (int r = 0; r < 16; ++r) macc[qhalf][r][lane] = oacc[r];
#pragma unroll
        for (int r = 0; r < 16; ++r) macc[qhalf][16 + r][lane] = lsacc[r];
    }
    __syncthreads();
    if (khalf == 1) return;
#pragma unroll
    for (int r = 0; r < 16; ++r) oacc[r] += macc[qhalf][r][lane];
#pragma unroll
    for (int r = 0; r < 16; ++r) lsacc[r] += macc[qhalf][16 + r][lane];

    // normalize rows (reg r of oacc and lsacc both belong to row
    // q=(r&3)+8*(r>>2)+4h) and transpose O via the endgame LDS tile
#pragma unroll
    for (int r = 0; r < 16; ++r) {
        const int q = (r & 3) + 8 * (r >> 2) + 4 * h;
        tile[q * PSTR + l31] = (u16)f2bfs(oacc[r] / lsacc[r]);
    }

    asm volatile("" ::: "memory");   // endgame only: order tile write->read

    // O A-fragments: row=q=l31, k-slots d=8h+e
    bfrag oa0 = *reinterpret_cast<const bfrag*>(tile + l31 * PSTR + 8 * h);
    bfrag oa1 = *reinterpret_cast<const bfrag*>(tile + l31 * PSTR + 16 + 8 * h);

    // OUT[q][o] = O_norm @ Wp^T + bias: col=o=l31, row=q=(r&3)+8*(r>>2)+4h
    f32x16 oc;
#pragma unroll
    for (int r = 0; r < 16; ++r) oc[r] = bias;
    oc = __builtin_amdgcn_mfma_f32_32x32x16_bf16(oa0, wf0, oc, 0, 0, 0);
    oc = __builtin_amdgcn_mfma_f32_32x32x16_bf16(oa1, wf1, oc, 0, 0, 0);

    // store: reg group rr holds q = qbase + 8*rr + 4h + {0,1,2,3} at o=l31
    float* ob = out + (size_t)(bg * D + l31) * N + qbase + 4 * h;
#pragma unroll
    for (int rr = 0; rr < 4; ++rr)
        *reinterpret_cast<float4*>(ob + 8 * rr) =
            make_float4(oc[4 * rr], oc[4 * rr + 1], oc[4 * rr + 2], oc[4 * rr + 3]);
}

extern "C" void kernel_launch(void* const* d_in, const int* in_sizes, int n_in,
                              void* d_out, int out_size, void* d_ws, size_t ws_size,
                              hipStream_t stream) {
    const float* x  = (const float*)d_in[0];
    const float* Wq = (const float*)d_in[1];
    const float* bq = (const float*)d_in[2];
    const float* Wk = (const float*)d_in[3];
    const float* bk = (const float*)d_in[4];
    const float* Wv = (const float*)d_in[5];
    const float* bv = (const float*)d_in[6];
    const float* Wp = (const float*)d_in[7];
    const float* bp = (const float*)d_in[8];
    float* out = (float*)d_out;

    u16* Qb = (u16*)d_ws;                        // [16][4096][32] bf16 = 4 MB
    u16* K2 = Qb + (size_t)NBG * N * D;          // [16][4][4096][8] = 4 MB
    u16* V2 = K2 + (size_t)NBG * N * D;          // [16][256][2][32][8] = 4 MB

    proj_kernel<<<dim3(N / 256, NBG, 3), 256, 0, stream>>>(x, Wq, bq, Wk, bk, Wv, bv, Qb, K2, V2);
    attn_kernel<<<dim3(NBG * (N / 64)), 256, 0, stream>>>(Qb, K2, V2, Wp, bp, out);
}

// Round 19
// 72.143 us; speedup vs baseline: 1.0019x; 1.0019x over previous
//
#include <hip/hip_runtime.h>
#include <hip/hip_bf16.h>

// SelfAttention b=2, heads=8, D=32, n=4096 (64x64).
// Pass 1 (proj_kernel, z=Q/K/V): x -> Q bf16 [bg][n][32] (pre-scaled by
//   SCALE*log2e), K2 bf16 [bg][dgrp=d/8][key][8], V2 bf16 sigma-ordered
//   [bg][key16grp][h][d][8] (r15-proven: PV A-frags = direct cvt_pk of
//   exp2 outputs, no cross-lane ops).
// Pass 2 (attn_kernel): 32x32 MFMA flash attention, 32 q/wave.
//   r17-proven loop: unroll x2 (two independent S->exp2->PV chains/iter),
//   K prefetch 1 pair ahead, lsum on the matrix pipe via mfma(P,ones).
//   r18: KEY-SPLIT -- 4 waves/block = (qhalf, khalf); khalf halves the
//   key range (32 pairs each) -> 4096 waves -> 4 waves/SIMD so the two
//   ~50%-busy pipes (r17: VALU 53 / MFMA 36) can interleave across more
//   contexts. Merge: khalf=1 writes fp32 oacc+lsacc to LDS (lane-major,
//   conflict-free), one __syncthreads, khalf=0 adds + runs the proven
//   endgame (LDS transpose -> Wp MFMA -> float4 stores).

constexpr int D = 32;
constexpr int N = 4096;
constexpr int NBG = 16;
constexpr float SCALE = 0.17677669529663687f;   // 32^-0.5
constexpr float LOG2E = 1.4426950408889634f;

using bfrag  = __attribute__((ext_vector_type(8))) short;   // 8 bf16
using s16x8  = __attribute__((ext_vector_type(8))) short;
using f32x16 = __attribute__((ext_vector_type(16))) float;
typedef unsigned short u16;
typedef unsigned int u32;

constexpr int PSTR = 34;            // endgame tile row stride in u16

__device__ __forceinline__ float fexp2(float x) { return __builtin_amdgcn_exp2f(x); }

__device__ __forceinline__ short f2bfs(float f) {
    __hip_bfloat16 h = __float2bfloat16(f);
    return (short)__builtin_bit_cast(u16, h);
}

__device__ __forceinline__ u32 cvt_pk_bf16(float lo, float hi) {
    u32 r;
    asm("v_cvt_pk_bf16_f32 %0, %1, %2" : "=v"(r) : "v"(lo), "v"(hi));
    return r;
}

// ---------------- pass 1: projections -> fragment-native bf16 scratch -----
__global__ __launch_bounds__(256) void proj_kernel(
    const float* __restrict__ x,
    const float* __restrict__ Wq, const float* __restrict__ bq,
    const float* __restrict__ Wk, const float* __restrict__ bk,
    const float* __restrict__ Wv, const float* __restrict__ bv,
    u16* __restrict__ Qb, u16* __restrict__ K2, u16* __restrict__ V2) {
    const int bg = blockIdx.y, g = bg & 7;
    const int z  = blockIdx.z;                       // 0=Q 1=K 2=V
    const int i  = blockIdx.x * 256 + threadIdx.x;   // key / pixel index

    const float* W  = (z == 0) ? Wq : (z == 1) ? Wk : Wv;
    const float* bb = (z == 0) ? bq : (z == 1) ? bk : bv;

    const float* xb = x + (size_t)bg * D * N;
    float xv[D];
#pragma unroll
    for (int d = 0; d < D; ++d) xv[d] = xb[(size_t)d * N + i];

    const float* w = W + g * D * D;
    float acc[D];
#pragma unroll
    for (int o = 0; o < D; ++o) {
        float a0 = 0.f, a1 = 0.f, a2 = 0.f, a3 = 0.f;
#pragma unroll
        for (int d = 0; d < D; d += 4) {
            a0 = fmaf(w[o * D + d    ], xv[d    ], a0);
            a1 = fmaf(w[o * D + d + 1], xv[d + 1], a1);
            a2 = fmaf(w[o * D + d + 2], xv[d + 2], a2);
            a3 = fmaf(w[o * D + d + 3], xv[d + 3], a3);
        }
        acc[o] = (a0 + a1) + (a2 + a3) + bb[g * D + o];
    }

    if (z == 0) {                                    // Q -> row [n][32]
        u16* dst = Qb + ((size_t)bg * N + i) * D;
#pragma unroll
        for (int t = 0; t < 4; ++t) {
            s16x8 v;
#pragma unroll
            for (int e = 0; e < 8; ++e) v[e] = f2bfs(acc[8 * t + e] * (SCALE * LOG2E));
            *reinterpret_cast<s16x8*>(dst + 8 * t) = v;
        }
    } else if (z == 1) {                             // K -> [dgrp][key][8]
        u16* kb2 = K2 + (size_t)bg * N * D;
#pragma unroll
        for (int t = 0; t < 4; ++t) {                // dgrp = t
            s16x8 v;
#pragma unroll
            for (int e = 0; e < 8; ++e) v[e] = f2bfs(acc[8 * t + e]);
            *reinterpret_cast<s16x8*>(kb2 + (size_t)t * N * 8 + (size_t)i * 8) = v;
        }
    } else {
        // V -> sigma-ordered [key16grp][h][d][8]:
        // key j=i&15 sits at h=(j>>2)&1, e=(j&3)+4*((j>>3)&1), matching the
        // S^T in-lane key order (row = (e&3)+8*(e>>2)+4h) -> no permswap.
        const int j  = i & 15;
        const int hh = (j >> 2) & 1;
        const int ee = (j & 3) + 4 * ((j >> 3) & 1);
        u16* vb2 = V2 + (size_t)bg * N * D + (size_t)(i >> 4) * 512 + hh * 256 + ee;
#pragma unroll
        for (int o = 0; o < D; ++o)
            vb2[o * 8] = (u16)f2bfs(acc[o]);
    }
}

// ---------------- pass 2: 32x32 MFMA flash attention, key-split ------------
__global__ __launch_bounds__(256) void attn_kernel(
    const u16* __restrict__ Qb, const u16* __restrict__ K2, const u16* __restrict__ V2,
    const float* __restrict__ Wp, const float* __restrict__ bp,
    float* __restrict__ out) {
    const int s = blockIdx.x;
    const int bg = s & 15, qt = s >> 4, g = bg & 7;   // bg fastest -> XCD L2 reuse
    const int wid = threadIdx.x >> 6;
    const int qhalf = wid >> 1, khalf = wid & 1;
    const int lane = threadIdx.x & 63;
    const int l31 = lane & 31, h = lane >> 5;
    const int qbase = qt * 64 + qhalf * 32;           // 32 q rows per wave

    __shared__ float macc[2][32][64];                 // khalf merge (16 KB)
    __shared__ u16 plds_all[2][32][PSTR];             // endgame transpose
    u16* tile = &plds_all[qhalf][0][0];

    const u16* Qw = Qb + (size_t)bg * N * D;
    const u16* Kw = K2 + (size_t)bg * N * D;
    const u16* Vw = V2 + (size_t)bg * N * D;

    // Q B-fragments (col=q=l31, k-slots d=8h+e), held whole loop
    const u16* qrow = Qw + (size_t)(qbase + l31) * D + 8 * h;
    bfrag qf0 = *reinterpret_cast<const bfrag*>(qrow);
    bfrag qf1 = *reinterpret_cast<const bfrag*>(qrow + 16);

    // Wp B-fragments (col=o=l31, k-slots d=8h+e) + bias
    bfrag wf0, wf1;
    {
        const float* wrow = Wp + (size_t)(g * D + l31) * D + 8 * h;
#pragma unroll
        for (int e = 0; e < 8; ++e) { wf0[e] = f2bfs(wrow[e]); wf1[e] = f2bfs(wrow[16 + e]); }
    }
    const float bias = bp[g * D + l31];

    // ones B-fragment (bf16 1.0) for the lsum MFMA
    bfrag onesf;
#pragma unroll
    for (int e = 0; e < 8; ++e) onesf[e] = (short)0x3F80;

    const f32x16 zf16 = {};
    f32x16 oacc  = {};
    f32x16 lsacc = {};

    // fragment-native bases + this wave's key-half offset
    const u16* kBase   = Kw + (size_t)h * N * 8 + (size_t)l31 * 8 + (size_t)khalf * (N / 2) * 8;
    const u16* kHiBase = kBase + 2 * N * 8;
    const u16* vBase   = Vw + h * 256 + l31 * 8 + (size_t)khalf * (N / 2) * 32;

    const int NTL = (N / 2) / 32;    // 64 local tiles per wave
    const int NPL = NTL / 2;         // 32 local pairs

    auto ldK = [&](int tt, int hi) {
        return *reinterpret_cast<const bfrag*>((hi ? kHiBase : kBase) + (size_t)tt * 256);
    };
    auto ldV = [&](int tt, int half) {
        return *reinterpret_cast<const bfrag*>(vBase + (size_t)tt * 1024 + half * 512);
    };

    // ---- prologue: S for local tiles 0,1; K for tiles 2,3 ----
    bfrag kA0 = ldK(0, 0), kA1 = ldK(0, 1);
    bfrag kB0 = ldK(1, 0), kB1 = ldK(1, 1);
    bfrag vA0 = ldV(0, 0), vA1 = ldV(0, 1);
    bfrag vB0 = ldV(1, 0), vB1 = ldV(1, 1);

    f32x16 sA = __builtin_amdgcn_mfma_f32_32x32x16_bf16(kA0, qf0, zf16, 0, 0, 0);
    sA = __builtin_amdgcn_mfma_f32_32x32x16_bf16(kA1, qf1, sA, 0, 0, 0);
    f32x16 sB = __builtin_amdgcn_mfma_f32_32x32x16_bf16(kB0, qf0, zf16, 0, 0, 0);
    sB = __builtin_amdgcn_mfma_f32_32x32x16_bf16(kB1, qf1, sB, 0, 0, 0);

    kA0 = ldK(2, 0); kA1 = ldK(2, 1);
    kB0 = ldK(3, 0); kB1 = ldK(3, 1);

    for (int t = 0; t < NPL - 1; ++t) {
        // S for pair t+1 -- independent of this pair's VALU work
        f32x16 snA = __builtin_amdgcn_mfma_f32_32x32x16_bf16(kA0, qf0, zf16, 0, 0, 0);
        snA = __builtin_amdgcn_mfma_f32_32x32x16_bf16(kA1, qf1, snA, 0, 0, 0);
        f32x16 snB = __builtin_amdgcn_mfma_f32_32x32x16_bf16(kB0, qf0, zf16, 0, 0, 0);
        snB = __builtin_amdgcn_mfma_f32_32x32x16_bf16(kB1, qf1, snB, 0, 0, 0);

        // prefetch K for pair t+2 (clamped), V for pair t+1
        const int t4 = (2 * t + 4 < NTL) ? (2 * t + 4) : (NTL - 1);
        const int t5 = (2 * t + 5 < NTL) ? (2 * t + 5) : (NTL - 1);
        kA0 = ldK(t4, 0); kA1 = ldK(t4, 1);
        kB0 = ldK(t5, 0); kB1 = ldK(t5, 1);
        bfrag vnA0 = ldV(2 * t + 2, 0), vnA1 = ldV(2 * t + 2, 1);
        bfrag vnB0 = ldV(2 * t + 3, 0), vnB1 = ldV(2 * t + 3, 1);

        // chain A: exp2 -> pack -> PV
        {
            float p[16];
#pragma unroll
            for (int r = 0; r < 16; ++r) p[r] = fexp2(sA[r]);
            uint4 f1 = make_uint4(cvt_pk_bf16(p[0],  p[1]),  cvt_pk_bf16(p[2],  p[3]),
                                  cvt_pk_bf16(p[4],  p[5]),  cvt_pk_bf16(p[6],  p[7]));
            uint4 f2 = make_uint4(cvt_pk_bf16(p[8],  p[9]),  cvt_pk_bf16(p[10], p[11]),
                                  cvt_pk_bf16(p[12], p[13]), cvt_pk_bf16(p[14], p[15]));
            const bfrag pf1 = __builtin_bit_cast(bfrag, f1);
            const bfrag pf2 = __builtin_bit_cast(bfrag, f2);
            oacc  = __builtin_amdgcn_mfma_f32_32x32x16_bf16(pf1, vA0,   oacc,  0, 0, 0);
            oacc  = __builtin_amdgcn_mfma_f32_32x32x16_bf16(pf2, vA1,   oacc,  0, 0, 0);
            lsacc = __builtin_amdgcn_mfma_f32_32x32x16_bf16(pf1, onesf, lsacc, 0, 0, 0);
            lsacc = __builtin_amdgcn_mfma_f32_32x32x16_bf16(pf2, onesf, lsacc, 0, 0, 0);
        }
        // chain B: exp2 -> pack -> PV
        {
            float p[16];
#pragma unroll
            for (int r = 0; r < 16; ++r) p[r] = fexp2(sB[r]);
            uint4 f1 = make_uint4(cvt_pk_bf16(p[0],  p[1]),  cvt_pk_bf16(p[2],  p[3]),
                                  cvt_pk_bf16(p[4],  p[5]),  cvt_pk_bf16(p[6],  p[7]));
            uint4 f2 = make_uint4(cvt_pk_bf16(p[8],  p[9]),  cvt_pk_bf16(p[10], p[11]),
                                  cvt_pk_bf16(p[12], p[13]), cvt_pk_bf16(p[14], p[15]));
            const bfrag pf1 = __builtin_bit_cast(bfrag, f1);
            const bfrag pf2 = __builtin_bit_cast(bfrag, f2);
            oacc  = __builtin_amdgcn_mfma_f32_32x32x16_bf16(pf1, vB0,   oacc,  0, 0, 0);
            oacc  = __builtin_amdgcn_mfma_f32_32x32x16_bf16(pf2, vB1,   oacc,  0, 0, 0);
            lsacc = __builtin_amdgcn_mfma_f32_32x32x16_bf16(pf1, onesf, lsacc, 0, 0, 0);
            lsacc = __builtin_amdgcn_mfma_f32_32x32x16_bf16(pf2, onesf, lsacc, 0, 0, 0);
        }

        sA = snA; sB = snB;
        vA0 = vnA0; vA1 = vnA1; vB0 = vnB0; vB1 = vnB1;
    }

    // ---- epilogue: final local pair ----
#pragma unroll
    for (int c = 0; c < 2; ++c) {
        const f32x16& sc = c ? sB : sA;
        float p[16];
#pragma unroll
        for (int r = 0; r < 16; ++r) p[r] = fexp2(sc[r]);
        uint4 f1 = make_uint4(cvt_pk_bf16(p[0],  p[1]),  cvt_pk_bf16(p[2],  p[3]),
                              cvt_pk_bf16(p[4],  p[5]),  cvt_pk_bf16(p[6],  p[7]));
        uint4 f2 = make_uint4(cvt_pk_bf16(p[8],  p[9]),  cvt_pk_bf16(p[10], p[11]),
                              cvt_pk_bf16(p[12], p[13]), cvt_pk_bf16(p[14], p[15]));
        const bfrag pf1 = __builtin_bit_cast(bfrag, f1);
        const bfrag pf2 = __builtin_bit_cast(bfrag, f2);
        oacc  = __builtin_amdgcn_mfma_f32_32x32x16_bf16(pf1, c ? vB0 : vA0, oacc,  0, 0, 0);
        oacc  = __builtin_amdgcn_mfma_f32_32x32x16_bf16(pf2, c ? vB1 : vA1, oacc,  0, 0, 0);
        lsacc = __builtin_amdgcn_mfma_f32_32x32x16_bf16(pf1, onesf, lsacc, 0, 0, 0);
        lsacc = __builtin_amdgcn_mfma_f32_32x32x16_bf16(pf2, onesf, lsacc, 0, 0, 0);
    }

    // ---- merge the two key-half waves of each q subtile ----
    if (khalf == 1) {
#pragma unroll
        for (int r = 0; r < 16; ++r) macc[qhalf][r][lane] = oacc[r];
#pragma unroll
        for (int r = 0; r < 16; ++r) macc[qhalf][16 + r][lane] = lsacc[r];
    }
    __syncthreads();
    if (khalf == 1) return;
#pragma unroll
    for (int r = 0; r < 16; ++r) oacc[r] += macc[qhalf][r][lane];
#pragma unroll
    for (int r = 0; r < 16; ++r) lsacc[r] += macc[qhalf][16 + r][lane];

    // normalize rows (reg r of oacc and lsacc both belong to row
    // q=(r&3)+8*(r>>2)+4h) and transpose O via the endgame LDS tile
#pragma unroll
    for (int r = 0; r < 16; ++r) {
        const int q = (r & 3) + 8 * (r >> 2) + 4 * h;
        tile[q * PSTR + l31] = (u16)f2bfs(oacc[r] / lsacc[r]);
    }

    asm volatile("" ::: "memory");   // endgame only: order tile write->read

    // O A-fragments: row=q=l31, k-slots d=8h+e
    bfrag oa0 = *reinterpret_cast<const bfrag*>(tile + l31 * PSTR + 8 * h);
    bfrag oa1 = *reinterpret_cast<const bfrag*>(tile + l31 * PSTR + 16 + 8 * h);

    // OUT[q][o] = O_norm @ Wp^T + bias: col=o=l31, row=q=(r&3)+8*(r>>2)+4h
    f32x16 oc;
#pragma unroll
    for (int r = 0; r < 16; ++r) oc[r] = bias;
    oc = __builtin_amdgcn_mfma_f32_32x32x16_bf16(oa0, wf0, oc, 0, 0, 0);
    oc = __builtin_amdgcn_mfma_f32_32x32x16_bf16(oa1, wf1, oc, 0, 0, 0);

    // store: reg group rr holds q = qbase + 8*rr + 4h + {0,1,2,3} at o=l31
    float* ob = out + (size_t)(bg * D + l31) * N + qbase + 4 * h;
#pragma unroll
    for (int rr = 0; rr < 4; ++rr)
        *reinterpret_cast<float4*>(ob + 8 * rr) =
            make_float4(oc[4 * rr], oc[4 * rr + 1], oc[4 * rr + 2], oc[4 * rr + 3]);
}

extern "C" void kernel_launch(void* const* d_in, const int* in_sizes, int n_in,
                              void* d_out, int out_size, void* d_ws, size_t ws_size,
                              hipStream_t stream) {
    const float* x  = (const float*)d_in[0];
    const float* Wq = (const float*)d_in[1];
    const float* bq = (const float*)d_in[2];
    const float* Wk = (const float*)d_in[3];
    const float* bk = (const float*)d_in[4];
    const float* Wv = (const float*)d_in[5];
    const float* bv = (const float*)d_in[6];
    const float* Wp = (const float*)d_in[7];
    const float* bp = (const float*)d_in[8];
    float* out = (float*)d_out;

    u16* Qb = (u16*)d_ws;                        // [16][4096][32] bf16 = 4 MB
    u16* K2 = Qb + (size_t)NBG * N * D;          // [16][4][4096][8] = 4 MB
    u16* V2 = K2 + (size_t)NBG * N * D;          // [16][256][2][32][8] = 4 MB

    proj_kernel<<<dim3(N / 256, NBG, 3), 256, 0, stream>>>(x, Wq, bq, Wk, bk, Wv, bv, Qb, K2, V2);
    attn_kernel<<<dim3(NBG * (N / 64)), 256, 0, stream>>>(Qb, K2, V2, Wp, bp, out);
}

// Round 20
// 67.440 us; speedup vs baseline: 1.0718x; 1.0697x over previous
//
#include <hip/hip_runtime.h>
#include <hip/hip_bf16.h>

// SelfAttention b=2, heads=8, D=32, n=4096 (64x64).
// Pass 1 (proj_kernel, z=Q/K/V): x -> Q bf16 [bg][n][32] (pre-scaled by
//   SCALE*log2e), K2 bf16 [bg][dgrp=d/8][key][8], V2 bf16 sigma-ordered
//   [bg][key16grp][h][d][8] (r15-proven: PV A-frags = direct cvt_pk of
//   exp2 outputs).
// Pass 2 (attn_kernel): 32x32 MFMA flash attention, 32 q/wave, 512 blocks
//   (key-split reverted: r18 showed wave count is irrelevant -- VALU+MFMA
//   busy SUM is the per-SIMD floor). r20 cuts both terms:
//   (1) ping-pong X/Y register states, 2 pairs per loop iter -> zero
//       loop-carried register copies (r17 burned ~64 VALU cyc/tile on
//       sA=snA / vA=vnA rotations);
//   (2) lsum back to fp32 add-tree (r13-proven): 32 VALU cyc/tile instead
//       of 64 MFMA cyc/tile -- MFMA work drops 6->4 per tile;
//   (3) Wp/bias loads hoisted to the endgame (shorter live ranges).
//   Endgame: shfl denominator reduce + LDS transpose + Wp MFMA (proven).

constexpr int D = 32;
constexpr int N = 4096;
constexpr int NBG = 16;
constexpr float SCALE = 0.17677669529663687f;   // 32^-0.5
constexpr float LOG2E = 1.4426950408889634f;

using bfrag  = __attribute__((ext_vector_type(8))) short;   // 8 bf16
using s16x8  = __attribute__((ext_vector_type(8))) short;
using f32x16 = __attribute__((ext_vector_type(16))) float;
typedef unsigned short u16;
typedef unsigned int u32;

constexpr int PSTR = 34;            // endgame tile row stride in u16

__device__ __forceinline__ float fexp2(float x) { return __builtin_amdgcn_exp2f(x); }

__device__ __forceinline__ short f2bfs(float f) {
    __hip_bfloat16 h = __float2bfloat16(f);
    return (short)__builtin_bit_cast(u16, h);
}

__device__ __forceinline__ u32 cvt_pk_bf16(float lo, float hi) {
    u32 r;
    asm("v_cvt_pk_bf16_f32 %0, %1, %2" : "=v"(r) : "v"(lo), "v"(hi));
    return r;
}

// ---------------- pass 1: projections -> fragment-native bf16 scratch -----
__global__ __launch_bounds__(256) void proj_kernel(
    const float* __restrict__ x,
    const float* __restrict__ Wq, const float* __restrict__ bq,
    const float* __restrict__ Wk, const float* __restrict__ bk,
    const float* __restrict__ Wv, const float* __restrict__ bv,
    u16* __restrict__ Qb, u16* __restrict__ K2, u16* __restrict__ V2) {
    const int bg = blockIdx.y, g = bg & 7;
    const int z  = blockIdx.z;                       // 0=Q 1=K 2=V
    const int i  = blockIdx.x * 256 + threadIdx.x;   // key / pixel index

    const float* W  = (z == 0) ? Wq : (z == 1) ? Wk : Wv;
    const float* bb = (z == 0) ? bq : (z == 1) ? bk : bv;

    const float* xb = x + (size_t)bg * D * N;
    float xv[D];
#pragma unroll
    for (int d = 0; d < D; ++d) xv[d] = xb[(size_t)d * N + i];

    const float* w = W + g * D * D;
    float acc[D];
#pragma unroll
    for (int o = 0; o < D; ++o) {
        float a0 = 0.f, a1 = 0.f, a2 = 0.f, a3 = 0.f;
#pragma unroll
        for (int d = 0; d < D; d += 4) {
            a0 = fmaf(w[o * D + d    ], xv[d    ], a0);
            a1 = fmaf(w[o * D + d + 1], xv[d + 1], a1);
            a2 = fmaf(w[o * D + d + 2], xv[d + 2], a2);
            a3 = fmaf(w[o * D + d + 3], xv[d + 3], a3);
        }
        acc[o] = (a0 + a1) + (a2 + a3) + bb[g * D + o];
    }

    if (z == 0) {                                    // Q -> row [n][32]
        u16* dst = Qb + ((size_t)bg * N + i) * D;
#pragma unroll
        for (int t = 0; t < 4; ++t) {
            s16x8 v;
#pragma unroll
            for (int e = 0; e < 8; ++e) v[e] = f2bfs(acc[8 * t + e] * (SCALE * LOG2E));
            *reinterpret_cast<s16x8*>(dst + 8 * t) = v;
        }
    } else if (z == 1) {                             // K -> [dgrp][key][8]
        u16* kb2 = K2 + (size_t)bg * N * D;
#pragma unroll
        for (int t = 0; t < 4; ++t) {                // dgrp = t
            s16x8 v;
#pragma unroll
            for (int e = 0; e < 8; ++e) v[e] = f2bfs(acc[8 * t + e]);
            *reinterpret_cast<s16x8*>(kb2 + (size_t)t * N * 8 + (size_t)i * 8) = v;
        }
    } else {
        // V -> sigma-ordered [key16grp][h][d][8]:
        // key j=i&15 sits at h=(j>>2)&1, e=(j&3)+4*((j>>3)&1), matching the
        // S^T in-lane key order (row = (e&3)+8*(e>>2)+4h) -> no permswap.
        const int j  = i & 15;
        const int hh = (j >> 2) & 1;
        const int ee = (j & 3) + 4 * ((j >> 3) & 1);
        u16* vb2 = V2 + (size_t)bg * N * D + (size_t)(i >> 4) * 512 + hh * 256 + ee;
#pragma unroll
        for (int o = 0; o < D; ++o)
            vb2[o * 8] = (u16)f2bfs(acc[o]);
    }
}

// exp2 + pack + PV + denominator adds for one 32-key tile
__device__ __forceinline__ void consume_tile(const f32x16& s, bfrag v0, bfrag v1,
                                             f32x16& oacc, float& lacc) {
    float p[16];
#pragma unroll
    for (int r = 0; r < 16; ++r) p[r] = fexp2(s[r]);
    lacc += ((((p[0] + p[1]) + (p[2] + p[3])) + ((p[4] + p[5]) + (p[6] + p[7])))
          +  (((p[8] + p[9]) + (p[10] + p[11])) + ((p[12] + p[13]) + (p[14] + p[15]))));
    uint4 f1 = make_uint4(cvt_pk_bf16(p[0],  p[1]),  cvt_pk_bf16(p[2],  p[3]),
                          cvt_pk_bf16(p[4],  p[5]),  cvt_pk_bf16(p[6],  p[7]));
    uint4 f2 = make_uint4(cvt_pk_bf16(p[8],  p[9]),  cvt_pk_bf16(p[10], p[11]),
                          cvt_pk_bf16(p[12], p[13]), cvt_pk_bf16(p[14], p[15]));
    oacc = __builtin_amdgcn_mfma_f32_32x32x16_bf16(__builtin_bit_cast(bfrag, f1), v0, oacc, 0, 0, 0);
    oacc = __builtin_amdgcn_mfma_f32_32x32x16_bf16(__builtin_bit_cast(bfrag, f2), v1, oacc, 0, 0, 0);
}

// ---------------- pass 2: 32x32 MFMA flash attention, ping-pong ------------
__global__ __launch_bounds__(256) void attn_kernel(
    const u16* __restrict__ Qb, const u16* __restrict__ K2, const u16* __restrict__ V2,
    const float* __restrict__ Wp, const float* __restrict__ bp,
    float* __restrict__ out) {
    const int s = blockIdx.x;
    const int bg = s & 15, qt = s >> 4, g = bg & 7;   // bg fastest -> XCD L2 reuse
    const int wid = threadIdx.x >> 6;
    const int lane = threadIdx.x & 63;
    const int l31 = lane & 31, h = lane >> 5;
    const int qbase = qt * 128 + wid * 32;            // 32 q rows per wave

    __shared__ u16 plds_all[4][32][PSTR];             // endgame transpose only
    u16* tile = &plds_all[wid][0][0];

    const u16* Qw = Qb + (size_t)bg * N * D;
    const u16* Kw = K2 + (size_t)bg * N * D;
    const u16* Vw = V2 + (size_t)bg * N * D;

    // Q B-fragments (col=q=l31, k-slots d=8h+e), held whole loop
    const u16* qrow = Qw + (size_t)(qbase + l31) * D + 8 * h;
    bfrag qf0 = *reinterpret_cast<const bfrag*>(qrow);
    bfrag qf1 = *reinterpret_cast<const bfrag*>(qrow + 16);

    const f32x16 zf16 = {};
    f32x16 oacc = {};
    float lacc = 0.f;

    // fragment-native bases: every in-loop load is 1KB contiguous per wave
    const u16* kBase   = Kw + (size_t)h * N * 8 + (size_t)l31 * 8;  // dgrp h, key l31
    const u16* kHiBase = kBase + 2 * N * 8;                         // dgrp h+2
    const u16* vBase   = Vw + h * 256 + l31 * 8;                    // h-group, d=l31

    const int NT = N / 32;           // 128 tiles
    const int NP = NT / 2;           // 64 pairs (even, >=4)

    auto ldK = [&](int tt, int hi) {
        return *reinterpret_cast<const bfrag*>((hi ? kHiBase : kBase) + (size_t)tt * 256);
    };
    auto ldV = [&](int tt, int half) {
        return *reinterpret_cast<const bfrag*>(vBase + (size_t)tt * 1024 + half * 512);
    };

    // K register set (single, reused): holds K for the pair whose S is next
    bfrag kA0 = ldK(0, 0), kA1 = ldK(0, 1);
    bfrag kB0 = ldK(1, 0), kB1 = ldK(1, 1);

    // ---- prologue: S for pair 0 into state X; kRegs -> K[pair 1]; V[pair 0] -> X
    f32x16 sAx = __builtin_amdgcn_mfma_f32_32x32x16_bf16(kA0, qf0, zf16, 0, 0, 0);
    sAx = __builtin_amdgcn_mfma_f32_32x32x16_bf16(kA1, qf1, sAx, 0, 0, 0);
    f32x16 sBx = __builtin_amdgcn_mfma_f32_32x32x16_bf16(kB0, qf0, zf16, 0, 0, 0);
    sBx = __builtin_amdgcn_mfma_f32_32x32x16_bf16(kB1, qf1, sBx, 0, 0, 0);

    kA0 = ldK(2, 0); kA1 = ldK(2, 1);
    kB0 = ldK(3, 0); kB1 = ldK(3, 1);

    bfrag vA0x = ldV(0, 0), vA1x = ldV(0, 1);
    bfrag vB0x = ldV(1, 0), vB1x = ldV(1, 1);

    f32x16 sAy, sBy;
    bfrag vA0y, vA1y, vB0y, vB1y;

    // STEP(cur->next, pn): build S[pn] from kRegs; kRegs <- K[pn+1];
    //                      V[pn] -> next; consume cur.
#define PAIR_STEP(SA_C, SB_C, VA0_C, VA1_C, VB0_C, VB1_C,                      \
                  SA_N, SB_N, VA0_N, VA1_N, VB0_N, VB1_N, PN)                  \
    SA_N = __builtin_amdgcn_mfma_f32_32x32x16_bf16(kA0, qf0, zf16, 0, 0, 0);   \
    SA_N = __builtin_amdgcn_mfma_f32_32x32x16_bf16(kA1, qf1, SA_N, 0, 0, 0);   \
    SB_N = __builtin_amdgcn_mfma_f32_32x32x16_bf16(kB0, qf0, zf16, 0, 0, 0);   \
    SB_N = __builtin_amdgcn_mfma_f32_32x32x16_bf16(kB1, qf1, SB_N, 0, 0, 0);   \
    kA0 = ldK(2 * (PN) + 2, 0); kA1 = ldK(2 * (PN) + 2, 1);                    \
    kB0 = ldK(2 * (PN) + 3, 0); kB1 = ldK(2 * (PN) + 3, 1);                    \
    VA0_N = ldV(2 * (PN), 0);     VA1_N = ldV(2 * (PN), 1);                    \
    VB0_N = ldV(2 * (PN) + 1, 0); VB1_N = ldV(2 * (PN) + 1, 1);                \
    consume_tile(SA_C, VA0_C, VA1_C, oacc, lacc);                              \
    consume_tile(SB_C, VB0_C, VB1_C, oacc, lacc);

    for (int p = 0; p < NP - 2; p += 2) {
        PAIR_STEP(sAx, sBx, vA0x, vA1x, vB0x, vB1x,
                  sAy, sBy, vA0y, vA1y, vB0y, vB1y, p + 1)
        PAIR_STEP(sAy, sBy, vA0y, vA1y, vB0y, vB1y,
                  sAx, sBx, vA0x, vA1x, vB0x, vB1x, p + 2)
    }
#undef PAIR_STEP

    // ---- epilogue: pair NP-2 (X) while building pair NP-1 (Y, no K load) ----
    sAy = __builtin_amdgcn_mfma_f32_32x32x16_bf16(kA0, qf0, zf16, 0, 0, 0);
    sAy = __builtin_amdgcn_mfma_f32_32x32x16_bf16(kA1, qf1, sAy, 0, 0, 0);
    sBy = __builtin_amdgcn_mfma_f32_32x32x16_bf16(kB0, qf0, zf16, 0, 0, 0);
    sBy = __builtin_amdgcn_mfma_f32_32x32x16_bf16(kB1, qf1, sBy, 0, 0, 0);
    vA0y = ldV(2 * (NP - 1), 0);     vA1y = ldV(2 * (NP - 1), 1);
    vB0y = ldV(2 * (NP - 1) + 1, 0); vB1y = ldV(2 * (NP - 1) + 1, 1);
    consume_tile(sAx, vA0x, vA1x, oacc, lacc);
    consume_tile(sBx, vB0x, vB1x, oacc, lacc);
    consume_tile(sAy, vA0y, vA1y, oacc, lacc);
    consume_tile(sBy, vB0y, vB1y, oacc, lacc);

    // ---- denominator: lane (l31,h) holds partial for q=l31 over its keys ----
    const float lsum = lacc + __shfl_xor(lacc, 32);
    const float linv = 1.0f / lsum;

    // normalize rows (oacc reg r -> row q=(r&3)+8*(r>>2)+4h, col d=l31) and
    // transpose O via the endgame LDS tile
#pragma unroll
    for (int r = 0; r < 16; ++r) {
        const int q = (r & 3) + 8 * (r >> 2) + 4 * h;
        const float ir = __shfl(linv, q);
        tile[q * PSTR + l31] = (u16)f2bfs(oacc[r] * ir);
    }

    asm volatile("" ::: "memory");   // endgame only: order tile write->read

    // Wp B-fragments + bias (loaded here -- not live through the loop)
    bfrag wf0, wf1;
    {
        const float* wrow = Wp + (size_t)(g * D + l31) * D + 8 * h;
#pragma unroll
        for (int e = 0; e < 8; ++e) { wf0[e] = f2bfs(wrow[e]); wf1[e] = f2bfs(wrow[16 + e]); }
    }
    const float bias = bp[g * D + l31];

    // O A-fragments: row=q=l31, k-slots d=8h+e
    bfrag oa0 = *reinterpret_cast<const bfrag*>(tile + l31 * PSTR + 8 * h);
    bfrag oa1 = *reinterpret_cast<const bfrag*>(tile + l31 * PSTR + 16 + 8 * h);

    // OUT[q][o] = O_norm @ Wp^T + bias: col=o=l31, row=q=(r&3)+8*(r>>2)+4h
    f32x16 oc;
#pragma unroll
    for (int r = 0; r < 16; ++r) oc[r] = bias;
    oc = __builtin_amdgcn_mfma_f32_32x32x16_bf16(oa0, wf0, oc, 0, 0, 0);
    oc = __builtin_amdgcn_mfma_f32_32x32x16_bf16(oa1, wf1, oc, 0, 0, 0);

    // store: reg group rr holds q = qbase + 8*rr + 4h + {0,1,2,3} at o=l31
    float* ob = out + (size_t)(bg * D + l31) * N + qbase + 4 * h;
#pragma unroll
    for (int rr = 0; rr < 4; ++rr)
        *reinterpret_cast<float4*>(ob + 8 * rr) =
            make_float4(oc[4 * rr], oc[4 * rr + 1], oc[4 * rr + 2], oc[4 * rr + 3]);
}

extern "C" void kernel_launch(void* const* d_in, const int* in_sizes, int n_in,
                              void* d_out, int out_size, void* d_ws, size_t ws_size,
                              hipStream_t stream) {
    const float* x  = (const float*)d_in[0];
    const float* Wq = (const float*)d_in[1];
    const float* bq = (const float*)d_in[2];
    const float* Wk = (const float*)d_in[3];
    const float* bk = (const float*)d_in[4];
    const float* Wv = (const float*)d_in[5];
    const float* bv = (const float*)d_in[6];
    const float* Wp = (const float*)d_in[7];
    const float* bp = (const float*)d_in[8];
    float* out = (float*)d_out;

    u16* Qb = (u16*)d_ws;                        // [16][4096][32] bf16 = 4 MB
    u16* K2 = Qb + (size_t)NBG * N * D;          // [16][4][4096][8] = 4 MB
    u16* V2 = K2 + (size_t)NBG * N * D;          // [16][256][2][32][8] = 4 MB

    proj_kernel<<<dim3(N / 256, NBG, 3), 256, 0, stream>>>(x, Wq, bq, Wk, bk, Wv, bv, Qb, K2, V2);
    attn_kernel<<<dim3(NBG * (N / 128)), 256, 0, stream>>>(Qb, K2, V2, Wp, bp, out);
}